// Round 4
// baseline (173.879 us; speedup 1.0000x reference)
//
#include <hip/hip_runtime.h>

// x shape (B, T, A, D) = (256, 2048, 22, 2) fp32
#define BB 256
#define TT 2048
#define AD 44                    // floats per (b,t) row
#define AD4 11                   // float4 chunks per row
#define F4_PER_B (TT * AD4)      // 22528 float4 per batch
#define X_BYTES ((size_t)BB * TT * AD * sizeof(float))  // 92,274,688

typedef float v4 __attribute__((ext_vector_type(4)));

// Runs AFTER a stream-ordered hipMemcpyAsync(out <- x). The bulk copy is
// delegated to ROCm's tuned blit (the harness's own fill kernels sustain
// 6.65 TB/s on this chip; my hand-rolled copies plateaued at ~2.7 TB/s).
// This kernel only (a) finds the NaN row range of its batch by scanning
// column (t,0,0) -- all L3-hot after the blit streamed x through L3 --
// and (b) overwrites the gap interior with interpolated rows.
__global__ __launch_bounds__(256) void fix_gap(const v4* __restrict__ x4,
                                               v4* __restrict__ out4) {
  const int tid = threadIdx.x;
  const int b = blockIdx.x;
  const float* xf = (const float*)x4;
  const size_t fbase = (size_t)b * (TT * AD);

  // Scan first element of every row (gap rows are entirely NaN).
  // 8 independent strided loads; L3-hit after the blit.
  float c[8];
#pragma unroll
  for (int k = 0; k < 8; ++k) {
    c[k] = xf[fbase + (size_t)(k * 256 + tid) * AD];
  }
  int tmin = TT, tmax = -1;
#pragma unroll
  for (int k = 0; k < 8; ++k) {
    if (c[k] != c[k]) {
      const int t = k * 256 + tid;
      tmin = min(tmin, t);
      tmax = max(tmax, t);
    }
  }

  // Wave reduce, then cross-wave reduce (4 waves).
#pragma unroll
  for (int d = 32; d > 0; d >>= 1) {
    tmin = min(tmin, __shfl_xor(tmin, d));
    tmax = max(tmax, __shfl_xor(tmax, d));
  }
  __shared__ int smin[4], smax[4];
  __shared__ int s_sh, e_sh;
  const int wid = tid >> 6;
  if ((tid & 63) == 0) {
    smin[wid] = tmin;
    smax[wid] = tmax;
  }
  __syncthreads();
  if (tid == 0) {
    int a = TT, z = -1;
#pragma unroll
    for (int i = 0; i < 4; ++i) {
      a = min(a, smin[i]);
      z = max(z, smax[i]);
    }
    if (z < 0) {          // defensive: no NaN -> no-op fix, in-bounds reads
      s_sh = 0;
      e_sh = 1;
    } else {
      s_sh = a - 1;       // row before first NaN
      e_sh = z + 1;       // row after last NaN
    }
  }
  __syncthreads();
  const int s = s_sh;
  const int e = e_sh;

  // Boundary rows (NaN-free by construction) -> LDS.
  __shared__ v4 sxs[AD4], sxe[AD4];
  const size_t base = (size_t)b * F4_PER_B;
  if (tid < AD4) sxs[tid] = x4[base + (size_t)s * AD4 + tid];
  if (tid >= 64 && tid < 64 + AD4) sxe[tid - 64] = x4[base + (size_t)e * AD4 + (tid - 64)];
  __syncthreads();

  // Interpolate gap interior rows s+1 .. e-1, overwriting the NaN rows the
  // blit copied (stream-ordered after the memcpy -> no race).
  const float inv = 1.0f / (float)(e - s);
  const int total = (e - s - 1) * AD4;
  for (int i = tid; i < total; i += 256) {
    const int dt = i / AD4;
    const int cch = i - dt * AD4;
    const int t = s + 1 + dt;
    const float w = (float)(dt + 1) * inv;   // (t - s)/(e - s)
    const float om = 1.0f - w;
    const v4 a = sxs[cch];
    const v4 z = sxe[cch];
    v4 r;
    r.x = a.x * om + z.x * w;
    r.y = a.y * om + z.y * w;
    r.z = a.z * om + z.z * w;
    r.w = a.w * om + z.w * w;
    out4[base + (size_t)t * AD4 + cch] = r;
  }
}

extern "C" void kernel_launch(void* const* d_in, const int* in_sizes, int n_in,
                              void* d_out, int out_size, void* d_ws, size_t ws_size,
                              hipStream_t stream) {
  const v4* x4 = (const v4*)d_in[0];
  v4* out4 = (v4*)d_out;

  // Bulk copy via ROCm's tuned blit path (graph-capture-safe async API).
  hipMemcpyAsync(d_out, d_in[0], X_BYTES, hipMemcpyDeviceToDevice, stream);

  // Then patch the gap (stream-ordered after the copy).
  fix_gap<<<BB, 256, 0, stream>>>(x4, out4);
}

// Round 5
// 162.445 us; speedup vs baseline: 1.0704x; 1.0704x over previous
//
#include <hip/hip_runtime.h>

// x shape (B, T, A, D) = (256, 2048, 22, 2) fp32
#define BB 256
#define TT 2048
#define AD 44                    // floats per (b,t) row
#define AD4 11                   // float4 chunks per row
#define F4_PER_B (TT * AD4)      // 22528 float4 per batch
#define ELEMS 8                  // float4 per thread (copy role)
#define BLK_F4 (256 * ELEMS)     // 2048 float4 per copy block
#define BLOCKS_PER_B 11
#define NCOPY (BB * BLOCKS_PER_B)
#define NBLK (BB + NCOPY)        // 256 fixers + 2816 copiers

typedef float v4 __attribute__((ext_vector_type(4)));

// Block-wide min/max reduce of (tmin, tmax). Result uniform in all threads.
__device__ __forceinline__ void block_minmax(const int tid, int& tmin, int& tmax,
                                             int* smin, int* smax) {
#pragma unroll
  for (int d = 32; d > 0; d >>= 1) {
    tmin = min(tmin, __shfl_xor(tmin, d));
    tmax = max(tmax, __shfl_xor(tmax, d));
  }
  const int wid = tid >> 6;
  if ((tid & 63) == 0) { smin[wid] = tmin; smax[wid] = tmax; }
  __syncthreads();
  if (tid == 0) {
    int a = smin[0], z = smax[0];
#pragma unroll
    for (int i = 1; i < 4; ++i) { a = min(a, smin[i]); z = max(z, smax[i]); }
    smin[0] = a; smax[0] = z;
  }
  __syncthreads();
  tmin = smin[0];
  tmax = smax[0];
  __syncthreads();               // allow smin/smax reuse by a later call
}

// Single dispatch, two block roles, zero cross-block synchronization.
// Roles write DISJOINT output regions: copy blocks store only NaN-free
// chunks (gap-interior rows are entirely NaN); fixer blocks write exactly
// the gap-interior rows. Regular stores everywhere (NT stores measured
// -8% in round 3: they force synchronous HBM write-out).
__global__ __launch_bounds__(256) void interp_one(const v4* __restrict__ x4,
                                                  v4* __restrict__ out4) {
  const int tid = threadIdx.x;

  if (blockIdx.x >= BB) {
    // ---------------- copy role ----------------
    const int cid = blockIdx.x - BB;
    const int b = cid / BLOCKS_PER_B;
    const int blk_in_b = cid - b * BLOCKS_PER_B;
    const size_t base = (size_t)b * F4_PER_B + (size_t)blk_in_b * BLK_F4;

    v4 v[ELEMS];
#pragma unroll
    for (int k = 0; k < ELEMS; ++k) {        // 8 independent loads in flight
      v[k] = x4[base + k * 256 + tid];
    }
#pragma unroll
    for (int k = 0; k < ELEMS; ++k) {
      const v4 w = v[k];
      const bool n = (w.x != w.x) || (w.y != w.y) || (w.z != w.z) || (w.w != w.w);
      if (!n) out4[base + k * 256 + tid] = w;
    }
    return;
  }

  // ---------------- fixer role (blockIdx 0..255: dispatched first,
  // hides under the copy) ----------------
  const int b = blockIdx.x;
  const float* xf = (const float*)x4;
  const size_t fbase = (size_t)b * (TT * AD);
  __shared__ int smin[4], smax[4];

  // Coarse scan: probe column (t,0,0) every 8th row. 256 probes touch
  // ~16KB of cache lines per batch (vs 128KB for the full scan).
  int tmin = TT, tmax = -1;
  {
    const int r = tid * 8;
    const float c = xf[fbase + (size_t)r * AD];
    if (c != c) { tmin = r; tmax = r; }
  }
  block_minmax(tid, tmin, tmax, smin, smax);

  if (tmax < 0) {
    // Gap shorter than 8 rows fell between samples (P~1.4%): full scan.
    tmin = TT; tmax = -1;
#pragma unroll
    for (int k = 0; k < 8; ++k) {
      const int r = k * 256 + tid;
      const float c = xf[fbase + (size_t)r * AD];
      if (c != c) { tmin = min(tmin, r); tmax = max(tmax, r); }
    }
    block_minmax(tid, tmin, tmax, smin, smax);
  } else {
    // NaN run is contiguous, so the true edges lie within 7 rows of the
    // coarse edges (coarse rows are multiples of 8; an earlier NaN at
    // cmin-8 would itself have been sampled).
    const int cmin = tmin, cmax = tmax;
    tmin = cmin; tmax = cmax;
    if (tid < 7) {
      const int r = cmin - 1 - tid;
      if (r >= 0) { const float c = xf[fbase + (size_t)r * AD]; if (c != c) tmin = r; }
    } else if (tid >= 64 && tid < 71) {
      const int r = cmax + 1 + (tid - 64);
      if (r < TT) { const float c = xf[fbase + (size_t)r * AD]; if (c != c) tmax = r; }
    }
    block_minmax(tid, tmin, tmax, smin, smax);
  }

  int s, e;
  if (tmax < 0) {                // defensive: no NaN -> no-op, in-bounds reads
    s = 0; e = 1;
  } else {
    s = tmin - 1;                // row before first NaN
    e = min(tmax + 1, TT - 1);   // row after last NaN (clamped for safety)
  }

  // Boundary rows (NaN-free by construction) -> LDS.
  __shared__ v4 sxs[AD4], sxe[AD4];
  const size_t base = (size_t)b * F4_PER_B;
  if (tid < AD4) sxs[tid] = x4[base + (size_t)s * AD4 + tid];
  if (tid >= 64 && tid < 64 + AD4) sxe[tid - 64] = x4[base + (size_t)e * AD4 + (tid - 64)];
  __syncthreads();

  // Interpolate gap interior rows s+1 .. e-1 (sole writer of this region).
  const float inv = 1.0f / (float)(e - s);
  const int total = (e - s - 1) * AD4;
  for (int i = tid; i < total; i += 256) {
    const int dt = i / AD4;
    const int cch = i - dt * AD4;
    const int t = s + 1 + dt;
    const float w = (float)(dt + 1) * inv;   // (t - s)/(e - s)
    const float om = 1.0f - w;
    const v4 a = sxs[cch];
    const v4 z = sxe[cch];
    v4 r;
    r.x = a.x * om + z.x * w;
    r.y = a.y * om + z.y * w;
    r.z = a.z * om + z.z * w;
    r.w = a.w * om + z.w * w;
    out4[base + (size_t)t * AD4 + cch] = r;
  }
}

extern "C" void kernel_launch(void* const* d_in, const int* in_sizes, int n_in,
                              void* d_out, int out_size, void* d_ws, size_t ws_size,
                              hipStream_t stream) {
  const v4* x4 = (const v4*)d_in[0];
  v4* out4 = (v4*)d_out;
  interp_one<<<NBLK, 256, 0, stream>>>(x4, out4);
}